// Round 1
// baseline (110.234 us; speedup 1.0000x reference)
//
#include <hip/hip_runtime.h>
#include <math.h>

// Problem constants
#define H 32
#define W 32
#define OH 94
#define OW 94
#define NMESH (OH * OW)   // 8836
#define B 4
#define M 4096
#define BM (B * M)        // 16384

// Linear padded mesh layout: 8 wave-uniform sub-ranges of 1120 entries each.
#define NSUB 8
#define SUBLEN 1120
#define NPAD (NSUB * SUBLEN)      // 8960 padded entries per batch
#define MESH_TOTAL (B * NPAD)     // 35840

// Kernel 1: bilinear mesh refine -> float4(-2x, -2y, -2z, ||m||^2); zero out.
// Premultiplying by -2 (exact in fp32) turns the distance partial into a pure
// 3-FMA chain: d = fma(px, -2mx, fma(py, -2my, fma(pz, -2mz, ||m||^2))).
// Layout is now LINEAR per batch (n = 0..8959), padding tail is sentinel.
__global__ __launch_bounds__(256) void mesh_init_kernel(
        const float* __restrict__ nm, float4* __restrict__ mesh4,
        float* __restrict__ out) {
    int e = blockIdx.x * 256 + threadIdx.x;
    if (e == 0) out[0] = 0.0f;
    if (e >= MESH_TOTAL) return;

    int b = e / NPAD;
    int n = e - b * NPAD;
    if (n >= NMESH) {  // padding sentinel: never the min
        mesh4[e] = make_float4(0.f, 0.f, 0.f, 3.0e38f);
        return;
    }
    int oy = n / OW;
    int ox = n - oy * OW;
    float ys = (float)oy / 3.0f;
    float xs = (float)ox / 3.0f;
    int y0 = (int)floorf(ys); if (y0 > H - 2) y0 = H - 2;
    int x0 = (int)floorf(xs); if (x0 > W - 2) x0 = W - 2;
    float wy = ys - (float)y0;
    float wx = xs - (float)x0;

    const float* base = nm + b * 3 * H * W;
    float vals[3];
#pragma unroll
    for (int c = 0; c < 3; ++c) {
        const float* p = base + c * H * W + y0 * W + x0;
        float v00 = p[0], v01 = p[1], v10 = p[W], v11 = p[W + 1];
        float top = v00 * (1.0f - wx) + v01 * wx;
        float bot = v10 * (1.0f - wx) + v11 * wx;
        vals[c] = top * (1.0f - wy) + bot * wy;
    }
    float nrm = vals[0] * vals[0] + vals[1] * vals[1] + vals[2] * vals[2];
    mesh4[e] = make_float4(-2.0f * vals[0], -2.0f * vals[1], -2.0f * vals[2], nrm);
}

// Kernel 2 (fused dist + reduce): 256 blocks x 512 threads.
// Block = 64 pc points x 8 waves; wave w handles sub-range w of the mesh
// (wave-uniform base via readfirstlane -> scalar s_load path preserved).
// LDS-combine the 8 sub-mins per point, add ||p||^2, wave-sum, one
// atomicAdd per block. Eliminates the minpart buffer and the 3rd kernel.
__global__ __launch_bounds__(512) void dist_kernel(
        const float* __restrict__ pc, const float4* __restrict__ mesh4,
        float* __restrict__ out) {
    int t = threadIdx.x;
    int lane = t & 63;
    int sub = __builtin_amdgcn_readfirstlane(t >> 6);  // wave-uniform -> SGPR
    int b = blockIdx.x >> 6;         // 4 batches
    int grp = blockIdx.x & 63;       // 64 point-groups per batch
    int i = grp * 64 + lane;         // pc point in [0, 4096)

    float px = pc[(b * 3 + 0) * M + i];
    float py = pc[(b * 3 + 1) * M + i];
    float pz = pc[(b * 3 + 2) * M + i];

    const float4* mp = mesh4 + b * NPAD + sub * SUBLEN;

    float m[8];
#pragma unroll
    for (int u = 0; u < 8; ++u) m[u] = 3.0e38f;

    for (int j = 0; j < SUBLEN; j += 8) {
#pragma unroll
        for (int u = 0; u < 8; ++u) {
            float4 a = mp[j + u];  // wave-uniform -> s_load_dwordx4
            float s = fmaf(px, a.x, fmaf(py, a.y, fmaf(pz, a.z, a.w)));
            m[u] = fminf(m[u], s);
        }
    }
    float v = fminf(fminf(fminf(m[0], m[1]), fminf(m[2], m[3])),
                    fminf(fminf(m[4], m[5]), fminf(m[6], m[7])));

    __shared__ float sm[NSUB * 64];
    sm[t] = v;  // t == sub*64 + lane exactly
    __syncthreads();

    if (t < 64) {
        float w_ = sm[t];
#pragma unroll
        for (int s2 = 1; s2 < NSUB; ++s2)
            w_ = fminf(w_, sm[s2 * 64 + t]);   // stride-64 floats: conflict-free
        float pn = fmaf(px, px, fmaf(py, py, pz * pz));
        float d = w_ + pn;
        // wave64 sum
        for (int off = 32; off > 0; off >>= 1)
            d += __shfl_down(d, off, 64);
        if (t == 0) atomicAdd(out, d * (1.0f / (float)BM));
    }
}

extern "C" void kernel_launch(void* const* d_in, const int* in_sizes, int n_in,
                              void* d_out, int out_size, void* d_ws, size_t ws_size,
                              hipStream_t stream) {
    const float* nm = (const float*)d_in[0];   // (4,3,32,32)
    const float* pc = (const float*)d_in[1];   // (4,3,4096)
    float* out = (float*)d_out;                // scalar

    float4* mesh4 = (float4*)d_ws;             // 35840 * 16 B = 573 KiB

    mesh_init_kernel<<<MESH_TOTAL / 256, 256, 0, stream>>>(nm, mesh4, out);
    dist_kernel<<<B * 64, 512, 0, stream>>>(pc, mesh4, out);
}